// Round 3
// baseline (369.700 us; speedup 1.0000x reference)
//
#include <hip/hip_runtime.h>
#include <math.h>

#define DIMC 16
#define KB 8
#define ROWS 16          // rows per block
#define BLOCK 256
#define PLANE 257        // LDS j-plane stride for w/h: readback bank = (j+tid)%32, conflict-free
#define SPLANE 259       // s j-plane stride: readback bank = (3*i+tid)%32, conflict-free
// c = (XY_MAX - XY_MIN) - K*MIN_BW = 2 - 8*0.001
#define C_SCALE 1.992f
#define MIN_BW 0.001f
#define MIN_KS 0.001f

#define LOG2E 1.44269504088896340736f
#define LN2   0.69314718055994530942f

__device__ __forceinline__ float fast_exp(float v) {
    return __builtin_amdgcn_exp2f(v * LOG2E);          // v_exp_f32
}
__device__ __forceinline__ float fast_log(float v) {
    return __builtin_amdgcn_logf(v) * LN2;             // v_log_f32
}
__device__ __forceinline__ float fast_rcp(float v) {
    return __builtin_amdgcn_rcpf(v);                   // v_rcp_f32
}
// softplus(v) = max(v,0) + log(1 + exp(-|v|)); 1+e in [1,2] so fast_log is safe
__device__ __forceinline__ float softplus_f(float v) {
    float e = fast_exp(-fabsf(v));
    return fmaxf(v, 0.0f) + fast_log(1.0f + e);
}

__global__ __launch_bounds__(BLOCK) void spline_coupling_kernel(
    const float* __restrict__ X,
    const float* __restrict__ W,
    const float* __restrict__ H,
    const float* __restrict__ S,
    const float* __restrict__ SH,
    float* __restrict__ OUT,
    int m)
{
    // k-major LDS planes: value for (row r, dim d, knot j) at [j*STRIDE + r*16 + d].
    __shared__ float w_lds[KB * PLANE];
    __shared__ float h_lds[KB * PLANE];
    __shared__ float s_lds[(KB - 1) * SPLANE];

    const int tid  = threadIdx.x;
    const int row0 = blockIdx.x * ROWS;
    const int rows = min(ROWS, m - row0);
    const int nelem = rows * DIMC;
    const bool active = tid < nelem;
    const int gid = row0 * DIMC + tid;      // tid = r*16 + d

    float x = active ? X[gid] : 0.0f;
    float ladJsum = 0.0f;

    for (int t = 0; t < 2; ++t) {
        const size_t rbase = (size_t)t * m + row0;
        const float4* wg = (const float4*)(W + rbase * (DIMC * KB));
        const float4* hg = (const float4*)(H + rbase * (DIMC * KB));
        const float*  sg = S + rbase * (DIMC * (KB - 1));

        __syncthreads();   // previous iteration's LDS reads done before restage

        // ---- stage W,H: rows*128 floats each, coalesced float4, transpose to k-major ----
        #pragma unroll
        for (int u = 0; u < 2; ++u) {
            int f4 = tid + u * BLOCK;                    // float4 index, 0..511
            if (f4 < (rows * DIMC * KB) / 4) {
                float4 wq = wg[f4];
                float4 hq = hg[f4];
                int flat = f4 << 2;                      // element index
                int a = ((flat >> 7) << 4) | ((flat >> 3) & 15);  // r*16 + d
                int j = flat & 7;                        // 0 or 4
                w_lds[(j + 0) * PLANE + a] = wq.x;
                w_lds[(j + 1) * PLANE + a] = wq.y;
                w_lds[(j + 2) * PLANE + a] = wq.z;
                w_lds[(j + 3) * PLANE + a] = wq.w;
                h_lds[(j + 0) * PLANE + a] = hq.x;
                h_lds[(j + 1) * PLANE + a] = hq.y;
                h_lds[(j + 2) * PLANE + a] = hq.z;
                h_lds[(j + 3) * PLANE + a] = hq.w;
            }
        }
        // ---- stage S: rows*112 floats, coalesced dword ----
        #pragma unroll
        for (int k = 0; k < 7; ++k) {
            int flat = tid + k * BLOCK;                  // 0..1791
            if (flat < rows * 112) {
                float sv = sg[flat];
                int r = flat / 112;                      // magic-mul
                int rem = flat - r * 112;
                int d = rem / 7;                         // magic-mul
                int j = rem - d * 7;
                s_lds[j * SPLANE + r * DIMC + d] = sv;
            }
        }
        float shift = active ? SH[rbase * DIMC + tid] : 0.0f;
        __syncthreads();

        // ---- compute (per-element, all operand reads now from LDS) ----
        // forward periodic shift: x in [-1,1), shift in [0,1) => v in [0,3)
        {
            float v = x + shift + 1.0f;
            if (v >= 2.0f) v -= 2.0f;
            x = v - 1.0f;
        }

        float wv[KB], hv[KB];
        #pragma unroll
        for (int j = 0; j < KB; ++j) {
            wv[j] = w_lds[j * PLANE + tid];
            hv[j] = h_lds[j * PLANE + tid];
        }

        // softmax(w) * c + MIN_BW
        float mx = wv[0];
        #pragma unroll
        for (int j = 1; j < KB; ++j) mx = fmaxf(mx, wv[j]);
        float sum = 0.0f;
        #pragma unroll
        for (int j = 0; j < KB; ++j) { wv[j] = fast_exp(wv[j] - mx); sum += wv[j]; }
        float inv = C_SCALE * fast_rcp(sum);
        #pragma unroll
        for (int j = 0; j < KB; ++j) wv[j] = wv[j] * inv + MIN_BW;

        // softmax(h) * c + MIN_BW
        mx = hv[0];
        #pragma unroll
        for (int j = 1; j < KB; ++j) mx = fmaxf(mx, hv[j]);
        sum = 0.0f;
        #pragma unroll
        for (int j = 0; j < KB; ++j) { hv[j] = fast_exp(hv[j] - mx); sum += hv[j]; }
        inv = C_SCALE * fast_rcp(sum);
        #pragma unroll
        for (int j = 0; j < KB; ++j) hv[j] = hv[j] * inv + MIN_BW;

        // fused cumsum + bin search + gather (select-based)
        int   idx = 0;
        float xk = -1.0f, yk = -1.0f;
        float x0 = -1.0f, y0 = -1.0f;
        float wk = wv[0], hk = hv[0];
        #pragma unroll
        for (int j = 1; j < KB; ++j) {
            xk += wv[j - 1];
            yk += hv[j - 1];
            bool ge = (x >= xk);
            idx = ge ? j     : idx;
            x0  = ge ? xk    : x0;
            y0  = ge ? yk    : y0;
            wk  = ge ? wv[j] : wk;
            hk  = ge ? hv[j] : hk;
        }

        // knot slopes: d[0]=d[K]=1, interior = softplus(s)+MIN_KS
        int i0 = idx - 1; if (i0 < 0) i0 = 0;
        int i1 = idx;     if (i1 > KB - 2) i1 = KB - 2;
        float s0 = s_lds[i0 * SPLANE + tid];   // conflict-free LDS gather
        float s1 = s_lds[i1 * SPLANE + tid];
        float d0 = (idx == 0)      ? 1.0f : softplus_f(s0) + MIN_KS;
        float d1 = (idx == KB - 1) ? 1.0f : softplus_f(s1) + MIN_KS;

        float rwk = fast_rcp(wk);
        float sk  = hk * rwk;
        float tt  = (x - x0) * rwk;
        float omt = 1.0f - tt;
        float a2  = d1 + d0 - 2.0f * sk;
        float den = sk + a2 * tt * omt;
        float rden = fast_rcp(den);
        float y   = y0 + hk * (sk * tt * tt + d0 * tt * omt) * rden;
        float num = d1 * tt * tt + 2.0f * sk * tt * omt + d0 * omt * omt;
        float skr = sk * rden;
        ladJsum += fast_log(skr * skr * num);   // 2log(sk)+log(num)-2log(den)

        // inverse periodic shift: arg in (-1, 2]
        {
            float v = y - shift + 1.0f;
            if (v < 0.0f)  v += 2.0f;
            if (v >= 2.0f) v -= 2.0f;
            x = v - 1.0f;
        }
    }

    if (active) {
        OUT[gid] = x;
        OUT[(size_t)m * DIMC + gid] = ladJsum;
    }
}

extern "C" void kernel_launch(void* const* d_in, const int* in_sizes, int n_in,
                              void* d_out, int out_size, void* d_ws, size_t ws_size,
                              hipStream_t stream) {
    const int total = in_sizes[0];        // m * DIM
    const int m = total / DIMC;
    const float* X  = (const float*)d_in[0];
    const float* W  = (const float*)d_in[1];
    const float* H  = (const float*)d_in[2];
    const float* S  = (const float*)d_in[3];
    const float* SH = (const float*)d_in[4];
    float* OUT = (float*)d_out;

    const int grid = (m + ROWS - 1) / ROWS;
    spline_coupling_kernel<<<grid, BLOCK, 0, stream>>>(X, W, H, S, SH, OUT, m);
}